// Round 15
// baseline (252.874 us; speedup 1.0000x reference)
//
#include <hip/hip_runtime.h>
#include <hip/hip_bf16.h>

#define N_NODES 8192
#define F_IN 256
#define F_OUT 128
#define NSTEP (N_NODES / 32)    // 256 K-steps of 32

typedef __attribute__((ext_vector_type(4))) float f32x4;
typedef __attribute__((ext_vector_type(8))) short bf16x8;
typedef __attribute__((ext_vector_type(4))) unsigned int u32x4;

static __device__ __forceinline__ short bfr(float x) {
    __hip_bfloat16 h = __float2bfloat16(x);   // RNE
    union { __hip_bfloat16 h; short s; } u; u.h = h;
    return u.s;
}

// Kernel 1: support^T[f][n] = sum_k X[n][k] * W[k][f]   (fp32 accum -> bf16)
__global__ __launch_bounds__(256) void support_kernel(
        const float* __restrict__ X, const float* __restrict__ W,
        unsigned short* __restrict__ supT) {
    __shared__ float Xs[32][68];
    __shared__ float Ws[64][128];
    const int t = threadIdx.x;
    const int n0 = blockIdx.x * 32;
    const int tc = t & 31;
    const int tr = t >> 5;
    float acc[4][4];
    #pragma unroll
    for (int i = 0; i < 4; ++i)
        #pragma unroll
        for (int j = 0; j < 4; ++j) acc[i][j] = 0.f;

    for (int k0 = 0; k0 < F_IN; k0 += 64) {
        __syncthreads();
        {
            const int r = t >> 3, kc = (t & 7) * 8;
            const float* src = X + (size_t)(n0 + r) * F_IN + k0 + kc;
            f32x4 v0 = *(const f32x4*)src;
            f32x4 v1 = *(const f32x4*)(src + 4);
            *(f32x4*)&Xs[r][kc]     = v0;
            *(f32x4*)&Xs[r][kc + 4] = v1;
        }
        {
            const int col = t & 127, kb = t >> 7;
            #pragma unroll
            for (int i = 0; i < 32; ++i) {
                const int k = kb + i * 2;
                Ws[k][col] = W[(size_t)(k0 + k) * F_OUT + col];
            }
        }
        __syncthreads();
        #pragma unroll 8
        for (int k = 0; k < 64; ++k) {
            const f32x4 b = *(const f32x4*)&Ws[k][tc * 4];
            float a[4];
            #pragma unroll
            for (int i = 0; i < 4; ++i) a[i] = Xs[tr * 4 + i][k];
            #pragma unroll
            for (int i = 0; i < 4; ++i) {
                acc[i][0] += a[i] * b.x; acc[i][1] += a[i] * b.y;
                acc[i][2] += a[i] * b.z; acc[i][3] += a[i] * b.w;
            }
        }
    }
    #pragma unroll
    for (int j = 0; j < 4; ++j) {
        const int col = tc * 4 + j;
        #pragma unroll
        for (int i = 0; i < 4; ++i) {
            supT[(size_t)col * N_NODES + n0 + tr * 4 + i] =
                (unsigned short)bfr(acc[i][j]);
        }
    }
}

// Kernel 2: out = adj @ support + bias. ZERO LDS, ZERO barriers, no split-K.
// 512 blocks x 256 thr (4 waves). Block = 16-row stripe; wave w = cols w*32.
// Both fragments loaded straight from global via asm global_load_dwordx4:
//   A: adj rows (HBM stream), fp32 -> v_cvt_pk_bf16_f32 in-reg.
//   B: supT [f][n] (2MB, L2-resident), bf16 k-contiguous.
// Depth-4 software pipeline, 4 NAMED register sets, manual vmcnt ledger
// (4 loads/step, 16 in flight; steady WAIT vmcnt(12)).
// __launch_bounds__(256, 1): min-occupancy floor -> VGPR cap 512, so the
// 16 staging sets stay register-resident (R14's VGPR=44 spill fix).
__global__ __launch_bounds__(256, 1) void gcn_kernel(
        const float* __restrict__ adj, const unsigned short* __restrict__ supT,
        const float* __restrict__ bias, float* __restrict__ out) {
    const int t = threadIdx.x;
    const int l = t & 63;
    const int w = t >> 6;                    // 0..3 -> col group
    const int row0 = blockIdx.x * 16;

    // per-lane byte offsets (32-bit voffset, SGPR base)
    unsigned int aoff = (unsigned)(row0 + (l & 15)) * (N_NODES * 4)
                      + ((l >> 4) * 32);                 // 8 floats of k
    unsigned int boff0 = (unsigned)(w * 32 + (l & 15)) * (N_NODES * 2)
                       + ((l >> 4) * 16);                // 8 bf16 of k
    unsigned int boff1 = boff0 + 16u * (N_NODES * 2);

    f32x4 acc0 = {0.f,0.f,0.f,0.f}, acc1 = {0.f,0.f,0.f,0.f};

    // 4 named pipeline sets: Axy = fp32 lo/hi, Bxy = two B rows
    f32x4 a0L, a0H, a1L, a1H, a2L, a2H, a3L, a3H;
    u32x4 b0P, b0Q, b1P, b1Q, b2P, b2Q, b3P, b3Q;

#define PK(dst, a, b) \
    asm("v_cvt_pk_bf16_f32 %0, %1, %2" : "=v"(dst) : "v"(a), "v"(b))

#define LDA(dst, off, imm) \
    asm volatile("global_load_dwordx4 %0, %1, %2 offset:" imm \
                 : "=v"(dst) : "v"(off), "s"(adj) : "memory")
#define LDB(dst, off, imm) \
    asm volatile("global_load_dwordx4 %0, %1, %2 offset:" imm \
                 : "=v"(dst) : "v"(off), "s"(supT) : "memory")

// issue one step's 4 loads (order: A-lo, A-hi, B0, B1)
#define ISSUE(rAL, rAH, rBP, rBQ, AIMM, AIMM16, BIMM) { \
    LDA(rAL, aoff, AIMM); \
    LDA(rAH, aoff, AIMM16); \
    LDB(rBP, boff0, BIMM); \
    LDB(rBQ, boff1, BIMM); }

#define WAIT(IMM) { \
    asm volatile("s_waitcnt vmcnt(" IMM ")" ::: "memory"); \
    __builtin_amdgcn_sched_barrier(0); }

// consume one set; optionally re-issue same set for step s+4 (imm 512/528/256)
#define BODY(rAL, rAH, rBP, rBQ, WIMM, DO_ISSUE) { \
    WAIT(WIMM); \
    u32x4 q; \
    PK(q.x, rAL.x, rAL.y); PK(q.y, rAL.z, rAL.w); \
    PK(q.z, rAH.x, rAH.y); PK(q.w, rAH.z, rAH.w); \
    bf16x8 am = __builtin_bit_cast(bf16x8, q); \
    acc0 = __builtin_amdgcn_mfma_f32_16x16x32_bf16( \
        am, __builtin_bit_cast(bf16x8, rBP), acc0, 0, 0, 0); \
    acc1 = __builtin_amdgcn_mfma_f32_16x16x32_bf16( \
        am, __builtin_bit_cast(bf16x8, rBQ), acc1, 0, 0, 0); \
    if (DO_ISSUE) { \
        ISSUE(rAL, rAH, rBP, rBQ, "512", "528", "256"); \
        aoff += 128; boff0 += 64; boff1 += 64; \
    } }

    // prologue: issue steps 0..3 into sets 0..3 (16 loads in flight)
    ISSUE(a0L, a0H, b0P, b0Q, "0",   "16",  "0");
    ISSUE(a1L, a1H, b1P, b1Q, "128", "144", "64");
    ISSUE(a2L, a2H, b2P, b2Q, "256", "272", "128");
    ISSUE(a3L, a3H, b3P, b3Q, "384", "400", "192");

    // main: steps 0..251 (63 groups of 4); each body re-issues step s+4
    for (int g = 0; g < (NSTEP - 4) / 4; ++g) {
        BODY(a0L, a0H, b0P, b0Q, "12", 1);
        BODY(a1L, a1H, b1P, b1Q, "12", 1);
        BODY(a2L, a2H, b2P, b2Q, "12", 1);
        BODY(a3L, a3H, b3P, b3Q, "12", 1);
    }
    // tail: steps 252..255, drain 12 -> 8 -> 4 -> 0
    BODY(a0L, a0H, b0P, b0Q, "12", 0);
    BODY(a1L, a1H, b1P, b1Q, "8",  0);
    BODY(a2L, a2H, b2P, b2Q, "4",  0);
    BODY(a3L, a3H, b3P, b3Q, "0",  0);

#undef BODY
#undef WAIT
#undef ISSUE
#undef LDA
#undef LDB
#undef PK

    // epilogue: C/D layout col = l&15, row = (l>>4)*4 + i; direct store + bias
    const int col0 = w * 32 + (l & 15);
    const int r0 = row0 + (l >> 4) * 4;
    const float bv0 = bias[col0];
    const float bv1 = bias[col0 + 16];
    #pragma unroll
    for (int i = 0; i < 4; ++i) {
        float* o = out + (size_t)(r0 + i) * F_OUT + col0;
        o[0]  = acc0[i] + bv0;
        o[16] = acc1[i] + bv1;
    }
}

extern "C" void kernel_launch(void* const* d_in, const int* in_sizes, int n_in,
                              void* d_out, int out_size, void* d_ws, size_t ws_size,
                              hipStream_t stream) {
    const float* input  = (const float*)d_in[0];
    const float* adj    = (const float*)d_in[1];
    const float* weight = (const float*)d_in[2];
    const float* bias   = (const float*)d_in[3];
    float* out = (float*)d_out;
    unsigned short* supT = (unsigned short*)d_ws;           // 2 MiB

    support_kernel<<<N_NODES / 32, 256, 0, stream>>>(input, weight, supT);
    gcn_kernel<<<N_NODES / 16, 256, 0, stream>>>(adj, supT, bias, out);
}

// Round 16
// 88.015 us; speedup vs baseline: 2.8731x; 2.8731x over previous
//
#include <hip/hip_runtime.h>
#include <hip/hip_bf16.h>

#define N_NODES 8192
#define F_IN 256
#define F_OUT 128

#define SPLITK 8
#define KQ (N_NODES / SPLITK)   // 1024
#define BK 64
#define NT (KQ / BK)            // 16
#define BM 128
#define A_LDS 16384             // A tile: 128 rows x 64 k x bf16
#define B_LDS 16384             // B tile: 128 f x 64 k x bf16
#define BUFB (A_LDS + B_LDS)    // 32 KB
// total 2*BUFB = 64 KB -> 2 blocks/CU

typedef __attribute__((ext_vector_type(4))) float f32x4;
typedef __attribute__((ext_vector_type(8))) short bf16x8;
typedef __attribute__((ext_vector_type(4))) unsigned int u32x4;

static __device__ __forceinline__ short bfr(float x) {
    __hip_bfloat16 h = __float2bfloat16(x);   // RNE
    union { __hip_bfloat16 h; short s; } u; u.h = h;
    return u.s;
}

static __device__ __forceinline__ void gload16(const void* g, void* l) {
    __builtin_amdgcn_global_load_lds(
        (const __attribute__((address_space(1))) unsigned int*)g,
        (__attribute__((address_space(3))) unsigned int*)l, 16, 0, 0);
}

// Kernel 1: support^T[f][n] = sum_k X[n][k] * W[k][f]   (fp32 accum -> bf16)
__global__ __launch_bounds__(256) void support_kernel(
        const float* __restrict__ X, const float* __restrict__ W,
        unsigned short* __restrict__ supT) {
    __shared__ float Xs[32][68];
    __shared__ float Ws[64][128];
    const int t = threadIdx.x;
    const int n0 = blockIdx.x * 32;
    const int tc = t & 31;
    const int tr = t >> 5;
    float acc[4][4];
    #pragma unroll
    for (int i = 0; i < 4; ++i)
        #pragma unroll
        for (int j = 0; j < 4; ++j) acc[i][j] = 0.f;

    for (int k0 = 0; k0 < F_IN; k0 += 64) {
        __syncthreads();
        {
            const int r = t >> 3, kc = (t & 7) * 8;
            const float* src = X + (size_t)(n0 + r) * F_IN + k0 + kc;
            f32x4 v0 = *(const f32x4*)src;
            f32x4 v1 = *(const f32x4*)(src + 4);
            *(f32x4*)&Xs[r][kc]     = v0;
            *(f32x4*)&Xs[r][kc + 4] = v1;
        }
        {
            const int col = t & 127, kb = t >> 7;
            #pragma unroll
            for (int i = 0; i < 32; ++i) {
                const int k = kb + i * 2;
                Ws[k][col] = W[(size_t)(k0 + k) * F_OUT + col];
            }
        }
        __syncthreads();
        #pragma unroll 8
        for (int k = 0; k < 64; ++k) {
            const f32x4 b = *(const f32x4*)&Ws[k][tc * 4];
            float a[4];
            #pragma unroll
            for (int i = 0; i < 4; ++i) a[i] = Xs[tr * 4 + i][k];
            #pragma unroll
            for (int i = 0; i < 4; ++i) {
                acc[i][0] += a[i] * b.x; acc[i][1] += a[i] * b.y;
                acc[i][2] += a[i] * b.z; acc[i][3] += a[i] * b.w;
            }
        }
    }
    #pragma unroll
    for (int j = 0; j < 4; ++j) {
        const int col = tc * 4 + j;
        #pragma unroll
        for (int i = 0; i < 4; ++i) {
            supT[(size_t)col * N_NODES + n0 + tr * 4 + i] =
                (unsigned short)bfr(acc[i][j]);
        }
    }
}

// Kernel 2: out += adj[:, hK] @ support[hK]  (+bias when h==0) via HW fp32
// atomics. BM=128, BK=64, split-K=8: grid 512 = 64 rb x 8 h, 512 thr
// (8 waves 2Mx4N, wave = 64x32 out). NT=16 -> HALF the barriers of R9,
// 2x compute per barrier (16 MFMA/wave/body). 64 KB LDS -> 2 blocks/CU.
//   A (HBM): reg-staged (R13-proven): 4 asm global_load_dwordx4 -> 16 fp32
//            -> 8 cvt_pk -> 2 swizzled ds_write_b128 (bf16 A tile, 16 KB).
//   B (L2):  global_load_lds x2 into 16KB tile (R9-proven swizzle).
// Per-body ledger: issue A(t+1)x4 + B(t+1)x2; COMPUTE(p) (~3200cy wall under
// HBM pacing) covers the latency; WAIT vmcnt(2) -> cvt+write A; WAITL 0 ->
// B + ds_writes done; single s_barrier.
__global__ __launch_bounds__(512, 4) void gcn_kernel(
        const float* __restrict__ adj, const unsigned short* __restrict__ supT,
        const float* __restrict__ bias, float* __restrict__ out) {
    __shared__ char lds[2 * BUFB];          // 64 KB
    const int t = threadIdx.x;
    const int l = t & 63;
    const int w = t >> 6;                   // 0..7
    const int rb = blockIdx.x & 63;
    const int h = blockIdx.x >> 6;          // K-eighth
    const int n0 = rb * BM;
    const int k0 = h * KQ;

    // ---- A reg-stage source: thread t -> row t>>2, 16 floats at (t&3)*16
    const int arow = t >> 2;                // 0..127
    const int atq = t & 3;
    unsigned int aoffv = (unsigned)((size_t)(n0 + arow) * N_NODES + k0) * 4
                       + (unsigned)(atq * 64);
    // A ds_write addrs (swizzled, region-relative): chunks c0=(t&3)*2, c0+1
    const int akw = arow & 7;
    const int awoff0 = arow * 128 + (((atq * 2)     ^ akw) * 16);
    const int awoff1 = arow * 128 + (((atq * 2 + 1) ^ akw) * 16);

    // ---- B staging (gload_lds, pre-swizzled source; R9-proven) ----
    const char* gB0 = (const char*)supT
        + ((size_t)(16 * w + (l >> 3)) * N_NODES + k0) * 2 + (((l & 7) ^ (l >> 3)) * 16);
    const char* gB1 = gB0 + (size_t)8 * N_NODES * 2;
    const int b_d0 = w * 2048;              // wave-uniform dest (HW adds lane*16)
    const int b_d1 = b_d0 + 1024;

    // ---- read-side offsets (region-relative) ----
    const int wm = w >> 2, wn = w & 3;
    const int akey = l & 7;
    int aoffm[4];
    #pragma unroll
    for (int m = 0; m < 4; ++m)
        aoffm[m] = (wm * 64 + 16 * m + (l & 15)) * 128;
    const int boff0 = (wn * 32 + (l & 15)) * 128;
    const int boff1 = boff0 + 16 * 128;
    const int bkey = l & 7;
    const int cg = l >> 4;                  // k-chunk group 0..3

    f32x4 acc[4][2];
    #pragma unroll
    for (int m = 0; m < 4; ++m)
        #pragma unroll
        for (int n = 0; n < 2; ++n) acc[m][n] = {0.f, 0.f, 0.f, 0.f};

    // single A-raw reg set (16 floats = 4 f32x4), staged 1 tile ahead
    f32x4 aR0, aR1, aR2, aR3;

#define PK(dst, a, b) \
    asm("v_cvt_pk_bf16_f32 %0, %1, %2" : "=v"(dst) : "v"(a), "v"(b))

#define LDA(dst, imm) \
    asm volatile("global_load_dwordx4 %0, %1, %2 offset:" imm \
                 : "=v"(dst) : "v"(aoffv), "s"(adj) : "memory")

#define STAGE_A() { \
    LDA(aR0, "0"); LDA(aR1, "16"); LDA(aR2, "32"); LDA(aR3, "48"); \
    aoffv += 256; }

#define STAGE_B(P) { \
    char* bb = &lds[(P) * BUFB + A_LDS]; \
    gload16(gB0, bb + b_d0); \
    gload16(gB1, bb + b_d1); \
    gB0 += 128; gB1 += 128; }

#define CVT_WRITE(P) { \
    u32x4 q0, q1; \
    PK(q0.x, aR0.x, aR0.y); PK(q0.y, aR0.z, aR0.w); \
    PK(q0.z, aR1.x, aR1.y); PK(q0.w, aR1.z, aR1.w); \
    PK(q1.x, aR2.x, aR2.y); PK(q1.y, aR2.z, aR2.w); \
    PK(q1.z, aR3.x, aR3.y); PK(q1.w, aR3.z, aR3.w); \
    char* ab = &lds[(P) * BUFB]; \
    *(u32x4*)(ab + awoff0) = q0; \
    *(u32x4*)(ab + awoff1) = q1; }

#define COMPUTE(P) { \
    const char* ab = &lds[(P) * BUFB]; \
    const char* bb = ab + A_LDS; \
    _Pragma("unroll") \
    for (int ks = 0; ks < 2; ++ks) { \
        const int c = ks * 4 + cg; \
        bf16x8 bf0 = *(const bf16x8*)(bb + boff0 + ((c ^ bkey) * 16)); \
        bf16x8 bf1 = *(const bf16x8*)(bb + boff1 + ((c ^ bkey) * 16)); \
        _Pragma("unroll") \
        for (int m = 0; m < 4; ++m) { \
            bf16x8 af = *(const bf16x8*)(ab + aoffm[m] + ((c ^ akey) * 16)); \
            acc[m][0] = __builtin_amdgcn_mfma_f32_16x16x32_bf16(af, bf0, acc[m][0], 0, 0, 0); \
            acc[m][1] = __builtin_amdgcn_mfma_f32_16x16x32_bf16(af, bf1, acc[m][1], 0, 0, 0); \
        } \
    } }

#define WAIT(IMM) { \
    asm volatile("s_waitcnt vmcnt(" IMM ")" ::: "memory"); \
    __builtin_amdgcn_sched_barrier(0); }

#define WAITL0() { \
    asm volatile("s_waitcnt vmcnt(0) lgkmcnt(0)" ::: "memory"); \
    __builtin_amdgcn_sched_barrier(0); }

#define BAR() { \
    __builtin_amdgcn_s_barrier(); \
    __builtin_amdgcn_sched_barrier(0); }

    // prologue: stage tile 0 into buffer 0
    STAGE_A();
    STAGE_B(0);
    WAIT("2");          // A regs landed (B x2 still in flight)
    CVT_WRITE(0);
    WAITL0();
    BAR();

    // bodies t = 0..NT-1 (NT=16, even/odd buffer parity)
    for (int t2 = 0; t2 < NT; t2 += 2) {
        // body t2 (p=0): stage tile t2+1 -> buf1
        STAGE_A();
        STAGE_B(1);
        COMPUTE(0);
        WAIT("2");
        CVT_WRITE(1);
        WAITL0();
        BAR();
        // body t2+1 (p=1): stage tile t2+2 -> buf0 (skip on last pair)
        if (t2 + 2 < NT) {
            STAGE_A();
            STAGE_B(0);
            COMPUTE(1);
            WAIT("2");
            CVT_WRITE(0);
            WAITL0();
            BAR();
        }
    }
    // final body (p=1): compute only
    COMPUTE(1);

#undef PK
#undef LDA
#undef STAGE_A
#undef STAGE_B
#undef CVT_WRITE
#undef COMPUTE
#undef WAIT
#undef WAITL0
#undef BAR

    // epilogue: atomic-accumulate into zeroed out; h==0 adds bias once.
    const int col = wn * 32 + (l & 15);
    const float bv0 = (h == 0) ? bias[col]      : 0.0f;
    const float bv1 = (h == 0) ? bias[col + 16] : 0.0f;
    const int rbase = n0 + wm * 64 + (l >> 4) * 4;
    #pragma unroll
    for (int m = 0; m < 4; ++m) {
        #pragma unroll
        for (int i = 0; i < 4; ++i) {
            float* o = out + (size_t)(rbase + 16 * m + i) * F_OUT + col;
            unsafeAtomicAdd(&o[0],  acc[m][0][i] + bv0);
            unsafeAtomicAdd(&o[16], acc[m][1][i] + bv1);
        }
    }
}

extern "C" void kernel_launch(void* const* d_in, const int* in_sizes, int n_in,
                              void* d_out, int out_size, void* d_ws, size_t ws_size,
                              hipStream_t stream) {
    const float* input  = (const float*)d_in[0];
    const float* adj    = (const float*)d_in[1];
    const float* weight = (const float*)d_in[2];
    const float* bias   = (const float*)d_in[3];
    float* out = (float*)d_out;
    unsigned short* supT = (unsigned short*)d_ws;           // 2 MiB

    hipMemsetAsync(d_out, 0, (size_t)out_size * sizeof(float), stream);
    support_kernel<<<N_NODES / 32, 256, 0, stream>>>(input, weight, supT);
    gcn_kernel<<<64 * SPLITK, 512, 0, stream>>>(adj, supT, bias, out);
}

// Round 17
// 78.318 us; speedup vs baseline: 3.2288x; 1.1238x over previous
//
#include <hip/hip_runtime.h>
#include <hip/hip_bf16.h>

#define N_NODES 8192
#define F_IN 256
#define F_OUT 128

#define SPLITK 4
#define KQ (N_NODES / SPLITK)   // 2048
#define BK 64
#define NT (KQ / BK)            // 32
#define ABYTES 16384            // A tile: 64 rows x 64 k x fp32
#define BBYTES 16384            // B tile: 128 f x 64 k x bf16
#define BUFB (ABYTES + BBYTES)  // 32 KB

typedef __attribute__((ext_vector_type(4))) float f32x4;
typedef __attribute__((ext_vector_type(8))) short bf16x8;
typedef __attribute__((ext_vector_type(4))) unsigned int u32x4;

static __device__ __forceinline__ short bfr(float x) {
    __hip_bfloat16 h = __float2bfloat16(x);   // RNE
    union { __hip_bfloat16 h; short s; } u; u.h = h;
    return u.s;
}

static __device__ __forceinline__ void gload16(const void* g, void* l) {
    __builtin_amdgcn_global_load_lds(
        (const __attribute__((address_space(1))) unsigned int*)g,
        (__attribute__((address_space(3))) unsigned int*)l, 16, 0, 0);
}

// Kernel 1: support^T[f][n] = sum_k X[n][k] * W[k][f]   (fp32 accum -> bf16)
// W staging vectorized (8 x f32x4 per thread vs 32 scalar loads).
__global__ __launch_bounds__(256) void support_kernel(
        const float* __restrict__ X, const float* __restrict__ W,
        unsigned short* __restrict__ supT) {
    __shared__ float Xs[32][68];
    __shared__ float Ws[64][128];
    const int t = threadIdx.x;
    const int n0 = blockIdx.x * 32;
    const int tc = t & 31;
    const int tr = t >> 5;
    float acc[4][4];
    #pragma unroll
    for (int i = 0; i < 4; ++i)
        #pragma unroll
        for (int j = 0; j < 4; ++j) acc[i][j] = 0.f;

    for (int k0 = 0; k0 < F_IN; k0 += 64) {
        __syncthreads();
        {
            const int r = t >> 3, kc = (t & 7) * 8;
            const float* src = X + (size_t)(n0 + r) * F_IN + k0 + kc;
            f32x4 v0 = *(const f32x4*)src;
            f32x4 v1 = *(const f32x4*)(src + 4);
            *(f32x4*)&Xs[r][kc]     = v0;
            *(f32x4*)&Xs[r][kc + 4] = v1;
        }
        {
            // W tile 64x128: thread t covers row (t>>5)+8i, cols (t&31)*4
            const int col4 = (t & 31) * 4;
            const int r0 = t >> 5;
            #pragma unroll
            for (int i = 0; i < 8; ++i) {
                const int k = r0 + i * 8;
                *(f32x4*)&Ws[k][col4] =
                    *(const f32x4*)&W[(size_t)(k0 + k) * F_OUT + col4];
            }
        }
        __syncthreads();
        #pragma unroll 8
        for (int k = 0; k < 64; ++k) {
            const f32x4 b = *(const f32x4*)&Ws[k][tc * 4];
            float a[4];
            #pragma unroll
            for (int i = 0; i < 4; ++i) a[i] = Xs[tr * 4 + i][k];
            #pragma unroll
            for (int i = 0; i < 4; ++i) {
                acc[i][0] += a[i] * b.x; acc[i][1] += a[i] * b.y;
                acc[i][2] += a[i] * b.z; acc[i][3] += a[i] * b.w;
            }
        }
    }
    #pragma unroll
    for (int j = 0; j < 4; ++j) {
        const int col = tc * 4 + j;
        #pragma unroll
        for (int i = 0; i < 4; ++i) {
            supT[(size_t)col * N_NODES + n0 + tr * 4 + i] =
                (unsigned short)bfr(acc[i][j]);
        }
    }
}

// Kernel 2: out += adj[:, hK] @ support[hK]  (+bias when h==0) via HW fp32
// atomics. BM=64, BK=64, split-K=4, grid 512 x 512 thr (8 waves 2Mx4N,
// wave = 32x32 out). R9-proven skeleton (best: 77.7us) with staging issue
// fine-interleaved into the compute phase (m196/m201 lever): A-stages ->
// ks=0 MFMA cluster -> B-stages -> ks=1 cluster -> vmcnt(0) fence + barrier.
__global__ __launch_bounds__(512, 4) void gcn_kernel(
        const float* __restrict__ adj, const unsigned short* __restrict__ supT,
        const float* __restrict__ bias, float* __restrict__ out) {
    __shared__ char lds[2 * BUFB];          // 64 KB -> 2 blocks/CU
    const int t = threadIdx.x;
    const int l = t & 63;
    const int w = t >> 6;                   // 0..7
    const int rb = blockIdx.x & 127;
    const int h = blockIdx.x >> 7;          // K-quarter
    const int n0 = rb * 64;
    const int k0 = h * KQ;

    // ---- staging sources (per-lane, pre-swizzled; R6/R9-proven) ----
    const int rA0 = 8 * w + (l >> 4);
    const int rA1 = rA0 + 4;
    const char* gA0 = (const char*)adj
        + ((size_t)(n0 + rA0) * N_NODES + k0) * 4 + (((l & 15) ^ (rA0 & 15)) * 16);
    const char* gA1 = (const char*)adj
        + ((size_t)(n0 + rA1) * N_NODES + k0) * 4 + (((l & 15) ^ (rA1 & 15)) * 16);
    const char* gB0 = (const char*)supT
        + ((size_t)(16 * w + (l >> 3)) * N_NODES + k0) * 2 + (((l & 7) ^ (l >> 3)) * 16);
    const char* gB1 = gB0 + (size_t)8 * N_NODES * 2;

    // wave-uniform LDS dest offsets (HW appends lane*16)
    const int a_d0 = w * 2048;
    const int a_d1 = a_d0 + 1024;
    const int b_d0 = ABYTES + w * 2048;
    const int b_d1 = b_d0 + 1024;

    // ---- read-side offsets ----
    const int wm = w >> 2, wn = w & 3;
    const int aoff0 = (wm * 32 + (l & 15)) * 256;
    const int aoff1 = aoff0 + 16 * 256;
    const int akey = l & 15;
    const int ac0 = (l >> 4) * 2;
    const int boff0 = ABYTES + (wn * 32 + (l & 15)) * 128;
    const int boff1 = boff0 + 16 * 128;
    const int bkey = l & 7;
    const int cb0 = l >> 4;

    f32x4 acc00 = {0.f,0.f,0.f,0.f}, acc01 = {0.f,0.f,0.f,0.f};
    f32x4 acc10 = {0.f,0.f,0.f,0.f}, acc11 = {0.f,0.f,0.f,0.f};

#define PK(dst, a, b) \
    asm("v_cvt_pk_bf16_f32 %0, %1, %2" : "=v"(dst) : "v"(a), "v"(b))

#define STAGE_A(BUF) { \
    char* bb = &lds[(BUF) * BUFB]; \
    gload16(gA0, bb + a_d0); \
    gload16(gA1, bb + a_d1); \
    gA0 += 256; gA1 += 256; }

#define STAGE_B(BUF) { \
    char* bb = &lds[(BUF) * BUFB]; \
    gload16(gB0, bb + b_d0); \
    gload16(gB1, bb + b_d1); \
    gB0 += 128; gB1 += 128; }

#define KSHALF(BUF, KS) { \
    const char* buf = &lds[(BUF) * BUFB]; \
    const int ca = (KS) * 8 + ac0; \
    f32x4 a0lo = *(const f32x4*)(buf + aoff0 + (((ca    ) ^ akey) * 16)); \
    f32x4 a0hi = *(const f32x4*)(buf + aoff0 + (((ca + 1) ^ akey) * 16)); \
    f32x4 a1lo = *(const f32x4*)(buf + aoff1 + (((ca    ) ^ akey) * 16)); \
    f32x4 a1hi = *(const f32x4*)(buf + aoff1 + (((ca + 1) ^ akey) * 16)); \
    const int cb = (KS) * 4 + cb0; \
    bf16x8 b0 = *(const bf16x8*)(buf + boff0 + ((cb ^ bkey) * 16)); \
    bf16x8 b1 = *(const bf16x8*)(buf + boff1 + ((cb ^ bkey) * 16)); \
    u32x4 p0, p1; \
    PK(p0.x, a0lo.x, a0lo.y); PK(p0.y, a0lo.z, a0lo.w); \
    PK(p0.z, a0hi.x, a0hi.y); PK(p0.w, a0hi.z, a0hi.w); \
    PK(p1.x, a1lo.x, a1lo.y); PK(p1.y, a1lo.z, a1lo.w); \
    PK(p1.z, a1hi.x, a1hi.y); PK(p1.w, a1hi.z, a1hi.w); \
    bf16x8 am0 = __builtin_bit_cast(bf16x8, p0); \
    bf16x8 am1 = __builtin_bit_cast(bf16x8, p1); \
    acc00 = __builtin_amdgcn_mfma_f32_16x16x32_bf16(am0, b0, acc00, 0, 0, 0); \
    acc01 = __builtin_amdgcn_mfma_f32_16x16x32_bf16(am0, b1, acc01, 0, 0, 0); \
    acc10 = __builtin_amdgcn_mfma_f32_16x16x32_bf16(am1, b0, acc10, 0, 0, 0); \
    acc11 = __builtin_amdgcn_mfma_f32_16x16x32_bf16(am1, b1, acc11, 0, 0, 0); }

#define FENCE_BARRIER() { \
    asm volatile("s_waitcnt vmcnt(0)" ::: "memory"); \
    __builtin_amdgcn_sched_barrier(0); \
    __builtin_amdgcn_s_barrier(); \
    __builtin_amdgcn_sched_barrier(0); }

    // prologue: tile 0 -> buffer 0
    STAGE_A(0);
    STAGE_B(0);
    FENCE_BARRIER();

    for (int tt = 0; tt < NT; ++tt) {
        const int cur = tt & 1;
        // fine interleave: A-stage issue / ks=0 cluster / B-stage issue / ks=1
        if (tt + 1 < NT) STAGE_A(cur ^ 1);
        KSHALF(cur, 0);
        if (tt + 1 < NT) STAGE_B(cur ^ 1);
        KSHALF(cur, 1);
        FENCE_BARRIER();
    }
#undef STAGE_A
#undef STAGE_B
#undef KSHALF
#undef FENCE_BARRIER
#undef PK

    // epilogue: atomic-accumulate into zeroed out; h==0 adds bias once.
    const int col = wn * 32 + (l & 15);
    const int row0 = n0 + wm * 32 + (l >> 4) * 4;
    const float bv0 = (h == 0) ? bias[col]      : 0.0f;
    const float bv1 = (h == 0) ? bias[col + 16] : 0.0f;
    #pragma unroll
    for (int i = 0; i < 4; ++i) {
        float* o0 = out + (size_t)(row0 + i) * F_OUT + col;
        float* o1 = out + (size_t)(row0 + i + 16) * F_OUT + col;
        unsafeAtomicAdd(&o0[0],  acc00[i] + bv0);
        unsafeAtomicAdd(&o0[16], acc01[i] + bv1);
        unsafeAtomicAdd(&o1[0],  acc10[i] + bv0);
        unsafeAtomicAdd(&o1[16], acc11[i] + bv1);
    }
}

extern "C" void kernel_launch(void* const* d_in, const int* in_sizes, int n_in,
                              void* d_out, int out_size, void* d_ws, size_t ws_size,
                              hipStream_t stream) {
    const float* input  = (const float*)d_in[0];
    const float* adj    = (const float*)d_in[1];
    const float* weight = (const float*)d_in[2];
    const float* bias   = (const float*)d_in[3];
    float* out = (float*)d_out;
    unsigned short* supT = (unsigned short*)d_ws;           // 2 MiB

    hipMemsetAsync(d_out, 0, (size_t)out_size * sizeof(float), stream);
    support_kernel<<<N_NODES / 32, 256, 0, stream>>>(input, weight, supT);
    gcn_kernel<<<128 * SPLITK, 512, 0, stream>>>(adj, supT, bias, out);
}